// Round 7
// baseline (279.168 us; speedup 1.0000x reference)
//
#include <hip/hip_runtime.h>
#include <hip/hip_bf16.h>
#include <math.h>

#define THREADS 256
typedef unsigned short ushortT;
typedef __attribute__((ext_vector_type(8))) short bf16x8;   // 8 bf16 = 4 VGPRs
typedef __attribute__((ext_vector_type(4))) float f32x4;

__device__ __forceinline__ void async16(const ushortT* g, ushortT* l) {
  __builtin_amdgcn_global_load_lds(
      (const __attribute__((address_space(1))) unsigned int*)g,
      (__attribute__((address_space(3))) unsigned int*)l, 16, 0, 0);
}

__device__ __forceinline__ ushortT f2bf(float f) {
  __hip_bfloat16 h = __float2bfloat16(f);
  return *reinterpret_cast<ushortT*>(&h);
}

// ---------------------------------------------------------------------------
// Kernel A: fused L2-norm + bf16 convert. One block per row (256 thr x float4).
// ---------------------------------------------------------------------------
__global__ __launch_bounds__(THREADS) void k_prep(const float* __restrict__ x,
                                                  ushortT* __restrict__ xn, int D) {
  __shared__ float red[4];
  const int row = blockIdx.x;
  const int tid = threadIdx.x;
  const int gid = row * (D / 4) + tid;
  const float4 v = reinterpret_cast<const float4*>(x)[gid];
  float s = v.x * v.x + v.y * v.y + v.z * v.z + v.w * v.w;
  #pragma unroll
  for (int off = 32; off; off >>= 1) s += __shfl_xor(s, off);
  if ((tid & 63) == 0) red[tid >> 6] = s;
  __syncthreads();
  const float tot = red[0] + red[1] + red[2] + red[3];
  const float rn = 1.0f / fmaxf(sqrtf(tot), 1e-12f);
  ushort4 o;
  o.x = f2bf(v.x * rn); o.y = f2bf(v.y * rn);
  o.z = f2bf(v.z * rn); o.w = f2bf(v.w * rn);
  reinterpret_cast<ushort4*>(xn)[gid] = o;
}

// ---------------------------------------------------------------------------
// Kernel B: 256x128 bf16 MFMA tiles (4 waves x 64x128), BK=32 double-buffered
// LDS, natural triangular order. Enumeration: blocks (rb, cb) with cb>=2*rb
// over 256-row x 128-col blocks (1056 blocks). "near-diag" blocks
// (cb<=2rb+1) lie inside a 256x256 diagonal supertile: orientation-1 only
// (full ordered coverage there), and their B-panel is a subset of the
// A-panel (B staging skipped). Far blocks emit both orientations; the
// orientation-2 value covers 256 cols = two 128-chunks, stored merged at
// slot 2rb with a neutral filler at slot 2rb+1 so every (row, slot) in
// partial[64][B] is written exactly once.
// Two-pass epilogue (max, then sum) to avoid sel[] register arrays;
// __launch_bounds__(256,2) -> 256 unified VGPR+AGPR cap, no spill.
// ---------------------------------------------------------------------------
__global__ __launch_bounds__(THREADS, 2) void k_main_mfma(const ushortT* __restrict__ xn,
                                                          const int* __restrict__ tgt,
                                                          float4* __restrict__ partial,
                                                          int D, int B) {
  __shared__ ushortT Asm[2][16 * 512];  // 2 x 16 KB: 256 rows x 32 k
  __shared__ ushortT Bsm[2][8 * 512];   // 2 x 8 KB:  128 rows x 32 k

  const int tid = threadIdx.x;
  const int lane = tid & 63;
  const int w = tid >> 6;

  // --- decode b -> (rb, cb), cb in [2rb, NCB)
  const int NRB = B / 256;          // 32
  const int C1 = 2 * NRB + 1;       // 65
  const int b = blockIdx.x;
  int rb = (int)((C1 - sqrtf((float)(C1 * C1 - 4 * b))) * 0.5f);
  while (rb * (C1 - rb) > b) --rb;
  while ((rb + 1) * (C1 - rb - 1) <= b) ++rb;
  const int cb = 2 * rb + (b - rb * (C1 - rb));
  const bool ndiag = (cb <= 2 * rb + 1);   // inside diagonal supertile

  const int i0 = rb * 256, j0 = cb * 128;

  // --- staging: lane fetches (row = lane&15, chunk = lane>>4) of its group
  const int sr = lane & 15, sc = lane >> 4;
  // A: 16 groups of 16 rows; wave w stages groups 4w..4w+3 (its own rows)
  const ushortT* gA[4];
  #pragma unroll
  for (int t = 0; t < 4; ++t)
    gA[t] = xn + (size_t)(i0 + 16 * (4 * w + t) + sr) * D + sc * 8;
  // B: 8 groups; wave w stages groups w and w+4 (skipped for near-diag)
  const ushortT* gB[2];
  #pragma unroll
  for (int u = 0; u < 2; ++u)
    gB[u] = xn + (size_t)(j0 + 16 * (w + 4 * u) + sr) * D + sc * 8;

  f32x4 acc[4][8];
  #pragma unroll
  for (int mt = 0; mt < 4; ++mt)
    #pragma unroll
    for (int nt = 0; nt < 8; ++nt)
      acc[mt][nt] = (f32x4){0.f, 0.f, 0.f, 0.f};

  // prologue: stage kk=0 into buffer 0
  #pragma unroll
  for (int t = 0; t < 4; ++t) async16(gA[t], &Asm[0][(4 * w + t) * 512]);
  if (!ndiag) {
    #pragma unroll
    for (int u = 0; u < 2; ++u) async16(gB[u], &Bsm[0][(w + 4 * u) * 512]);
  }
  __syncthreads();

  const int boffg = ndiag ? (cb - 2 * rb) * 8 : 0;  // group offset for b-frags
  const int kiters = D / 32;
  for (int kk = 0; kk < kiters; ++kk) {
    const int cur = kk & 1;
    if (kk + 1 < kiters) {
      const size_t ko = (size_t)(kk + 1) * 32;
      #pragma unroll
      for (int t = 0; t < 4; ++t)
        async16(gA[t] + ko, &Asm[cur ^ 1][(4 * w + t) * 512]);
      if (!ndiag) {
        #pragma unroll
        for (int u = 0; u < 2; ++u)
          async16(gB[u] + ko, &Bsm[cur ^ 1][(w + 4 * u) * 512]);
      }
    }
    const ushortT* Ab = &Asm[cur][0];
    const ushortT* Bb = ndiag ? &Asm[cur][boffg * 512] : &Bsm[cur][0];
    bf16x8 afr[4];
    #pragma unroll
    for (int mt = 0; mt < 4; ++mt)
      afr[mt] = *reinterpret_cast<const bf16x8*>(&Ab[(4 * w + mt) * 512 + lane * 8]);
    #pragma unroll
    for (int h = 0; h < 2; ++h) {
      bf16x8 bfr[4];
      #pragma unroll
      for (int n4 = 0; n4 < 4; ++n4)
        bfr[n4] = *reinterpret_cast<const bf16x8*>(&Bb[(h * 4 + n4) * 512 + lane * 8]);
      #pragma unroll
      for (int mt = 0; mt < 4; ++mt)
        #pragma unroll
        for (int n4 = 0; n4 < 4; ++n4)
          acc[mt][h * 4 + n4] =
              __builtin_amdgcn_mfma_f32_16x16x32_bf16(afr[mt], bfr[n4], acc[mt][h * 4 + n4], 0, 0, 0);
    }
    __syncthreads();
  }

  // --- epilogue. C/D layout: col = lane&15, row = (lane>>4)*4 + reg
  const int q = lane >> 4, c = lane & 15;
  int tj[8];
  #pragma unroll
  for (int nt = 0; nt < 8; ++nt) tj[nt] = tgt[j0 + nt * 16 + c];
  int tir[16];
  #pragma unroll
  for (int mt = 0; mt < 4; ++mt) {
    const int4 t4 = *reinterpret_cast<const int4*>(tgt + i0 + w * 64 + mt * 16 + q * 4);
    tir[mt * 4 + 0] = t4.x; tir[mt * 4 + 1] = t4.y;
    tir[mt * 4 + 2] = t4.z; tir[mt * 4 + 3] = t4.w;
  }

  // orientation 1: rows of this block (256), cols = this block's 128
  #pragma unroll
  for (int mt = 0; mt < 4; ++mt) {
    #pragma unroll
    for (int reg = 0; reg < 4; ++reg) {
      const int i = i0 + w * 64 + mt * 16 + q * 4 + reg;
      const int ti = tir[mt * 4 + reg];
      float m = -1e30f, sn = 0.f;
      #pragma unroll
      for (int nt = 0; nt < 8; ++nt) {          // pass 1: masked max + neg sum
        const float s = acc[mt][nt][reg];
        const int j = j0 + nt * 16 + c;
        const bool same = (tj[nt] == ti);
        const bool v = same && (j != i);
        const float lp = (fminf(s, 1.25f) - 1.25f) * fmaf(s, 64.f, -48.f);
        m = v ? fmaxf(m, lp) : m;
        const float ln = (fmaxf(s, -0.25f) + 0.25f) * fmaf(s, 64.f, -16.f);
        sn += same ? 0.f : __expf(ln);
      }
      #pragma unroll
      for (int off = 1; off < 16; off <<= 1) m = fmaxf(m, __shfl_xor(m, off));
      float sp = 0.f;
      #pragma unroll
      for (int nt = 0; nt < 8; ++nt) {          // pass 2: rescaled pos sum
        const float s = acc[mt][nt][reg];
        const int j = j0 + nt * 16 + c;
        const bool v = (tj[nt] == ti) && (j != i);
        const float lp = (fminf(s, 1.25f) - 1.25f) * fmaf(s, 64.f, -48.f);
        sp += v ? __expf(lp - m) : 0.f;
      }
      #pragma unroll
      for (int off = 1; off < 16; off <<= 1) {
        sp += __shfl_xor(sp, off);
        sn += __shfl_xor(sn, off);
      }
      if (c == 0) {
        float4 o; o.x = m; o.y = sp; o.z = sn; o.w = 0.f;
        partial[(size_t)cb * B + i] = o;
      }
    }
  }

  // orientation 2 (far blocks only): cols as LSE-rows over this block's 256 rows
  if (!ndiag) {
    float4* eo = reinterpret_cast<float4*>(&Asm[0][0]);  // [4 waves][128] = 8 KB
    #pragma unroll
    for (int nt = 0; nt < 8; ++nt) {
      const int jt = tj[nt];
      float m = -1e30f, sn = 0.f;
      #pragma unroll
      for (int mt = 0; mt < 4; ++mt)
        #pragma unroll
        for (int reg = 0; reg < 4; ++reg) {     // pass 1
          const float s = acc[mt][nt][reg];
          const bool same = (tir[mt * 4 + reg] == jt);  // j != i (far block)
          const float lp = (fminf(s, 1.25f) - 1.25f) * fmaf(s, 64.f, -48.f);
          m = same ? fmaxf(m, lp) : m;
          const float ln = (fmaxf(s, -0.25f) + 0.25f) * fmaf(s, 64.f, -16.f);
          sn += same ? 0.f : __expf(ln);
        }
      m = fmaxf(m, __shfl_xor(m, 16));
      m = fmaxf(m, __shfl_xor(m, 32));
      float sp = 0.f;
      #pragma unroll
      for (int mt = 0; mt < 4; ++mt)
        #pragma unroll
        for (int reg = 0; reg < 4; ++reg) {     // pass 2
          const float s = acc[mt][nt][reg];
          const bool same = (tir[mt * 4 + reg] == jt);
          const float lp = (fminf(s, 1.25f) - 1.25f) * fmaf(s, 64.f, -48.f);
          sp += same ? __expf(lp - m) : 0.f;
        }
      sp += __shfl_xor(sp, 16); sp += __shfl_xor(sp, 32);
      sn += __shfl_xor(sn, 16); sn += __shfl_xor(sn, 32);
      if (q == 0) {
        float4 o; o.x = m; o.y = sp; o.z = sn; o.w = 0.f;
        eo[w * 128 + nt * 16 + c] = o;
      }
    }
    __syncthreads();
    if (tid < 128) {   // merge the 4 wave-partials, write merged + neutral slot
      float mm = -1e30f, ms = 0.f, mn = 0.f;
      #pragma unroll
      for (int ww = 0; ww < 4; ++ww) {
        const float4 p = eo[ww * 128 + tid];
        const float nm = fmaxf(mm, p.x);
        ms = ms * __expf(mm - nm) + p.y * __expf(p.x - nm);
        mm = nm;
        mn += p.z;
      }
      float4 o; o.x = mm; o.y = ms; o.z = mn; o.w = 0.f;
      partial[(size_t)(2 * rb) * B + j0 + tid] = o;
      float4 z; z.x = -1e30f; z.y = 0.f; z.z = 0.f; z.w = 0.f;
      partial[(size_t)(2 * rb + 1) * B + j0 + tid] = z;
    }
  }
}

// ---------------------------------------------------------------------------
// Kernel C: fold 64 per-colblock partials per row -> row loss. One wave/row.
// ---------------------------------------------------------------------------
__global__ __launch_bounds__(THREADS) void k_reduce(const float4* __restrict__ partial,
                                                    float* __restrict__ row_loss,
                                                    int B) {
  const int lane = threadIdx.x & 63;
  const int row = blockIdx.x * 4 + (threadIdx.x >> 6);
  const float4 p = partial[(size_t)lane * B + row];
  float mp = p.x, sp = p.y, sn = p.z;
  #pragma unroll
  for (int off = 1; off < 64; off <<= 1) {
    const float m2 = __shfl_xor(mp, off), s2 = __shfl_xor(sp, off);
    const float nm = fmaxf(mp, m2);
    sp = sp * __expf(mp - nm) + s2 * __expf(m2 - nm);
    mp = nm;
    sn += __shfl_xor(sn, off);
  }
  if (lane == 0) {
    float loss = -1.0f;
    if (sp > 0.f && sn > 0.f) {
      const float z = mp + logf(sp) + logf(sn);
      loss = (z > 0.f) ? (z + log1pf(__expf(-z))) : log1pf(__expf(z));
    }
    row_loss[row] = loss;
  }
}

// ---------------------------------------------------------------------------
// Kernel D: masked mean over rows. One block.
// ---------------------------------------------------------------------------
__global__ __launch_bounds__(THREADS) void k_final(const float* __restrict__ row_loss,
                                                   float* __restrict__ out, int B) {
  __shared__ float ssum[4];
  __shared__ float scnt[4];
  const int tid = threadIdx.x;
  float sum = 0.f, cnt = 0.f;
  for (int i = tid; i < B; i += THREADS) {
    const float l = row_loss[i];
    if (l >= 0.f) { sum += l; cnt += 1.f; }
  }
  #pragma unroll
  for (int off = 32; off; off >>= 1) {
    sum += __shfl_xor(sum, off);
    cnt += __shfl_xor(cnt, off);
  }
  if ((tid & 63) == 0) { ssum[tid >> 6] = sum; scnt[tid >> 6] = cnt; }
  __syncthreads();
  if (tid == 0) {
    float ts = 0.f, tc = 0.f;
    #pragma unroll
    for (int w = 0; w < 4; ++w) { ts += ssum[w]; tc += scnt[w]; }
    out[0] = ts / fmaxf(tc, 1.f);
  }
}

// ---------------------------------------------------------------------------
extern "C" void kernel_launch(void* const* d_in, const int* in_sizes, int n_in,
                              void* d_out, int out_size, void* d_ws, size_t ws_size,
                              hipStream_t stream) {
  const float* x = (const float*)d_in[0];
  const int* tgt = (const int*)d_in[1];
  float* out = (float*)d_out;
  const int B = in_sizes[1];
  const int D = in_sizes[0] / B;
  const int NRB = B / 256;                       // 32
  const int nblocks = NRB * (2 * NRB + 1) - NRB * NRB;  // sum(64-2r) = 1056

  ushortT* xn = (ushortT*)d_ws;                                   // B*D bf16 (16 MB)
  float4* partial = (float4*)((char*)d_ws + (size_t)B * D * 2);   // 64*B float4 (8 MB)
  float* row_loss = (float*)((char*)d_ws + (size_t)B * D * 2 + (size_t)(B / 128) * B * 16);

  k_prep<<<B, THREADS, 0, stream>>>(x, xn, D);
  k_main_mfma<<<nblocks, THREADS, 0, stream>>>(xn, tgt, partial, D, B);
  k_reduce<<<B / 4, THREADS, 0, stream>>>(partial, row_loss, B);
  k_final<<<1, THREADS, 0, stream>>>(row_loss, out, B);
}